// Round 1
// baseline (599.728 us; speedup 1.0000x reference)
//
#include <hip/hip_runtime.h>
#include <math.h>

#define F_IN 165
#define HID 16
#define NCLS 2

// ---- degree: deg[dst] += 1 over all edges ----
__global__ __launch_bounds__(256) void k_deg(const int* __restrict__ dst,
                                             float* __restrict__ deg, int E) {
    int i = blockIdx.x * 256 + threadIdx.x;
    if (i < E) atomicAdd(&deg[dst[i]], 1.0f);
}

// ---- dinv_sqrt = rsqrt(deg + 1) in place ----
__global__ __launch_bounds__(256) void k_dinv(float* __restrict__ deg, int N) {
    int i = blockIdx.x * 256 + threadIdx.x;
    if (i < N) deg[i] = rsqrtf(deg[i] + 1.0f);
}

// ---- h1 = x @ W1   (2 rows per thread, W1 read wave-uniform -> SGPRs) ----
__global__ __launch_bounds__(256) void k_gemm1(const float* __restrict__ x,
                                               const float* __restrict__ W1,
                                               float* __restrict__ h1, int N) {
    int r0 = blockIdx.x * 512 + threadIdx.x;
    int r1 = r0 + 256;
    float accA[HID], accB[HID];
#pragma unroll
    for (int j = 0; j < HID; ++j) { accA[j] = 0.f; accB[j] = 0.f; }
    bool hasA = r0 < N, hasB = r1 < N;
    const float* xa = x + (long long)r0 * F_IN;
    const float* xb = x + (long long)r1 * F_IN;
    for (int k = 0; k < F_IN; ++k) {
        float a = hasA ? xa[k] : 0.f;
        float b = hasB ? xb[k] : 0.f;
#pragma unroll
        for (int j = 0; j < HID; ++j) {
            float w = W1[k * HID + j];   // wave-uniform address -> scalar load
            accA[j] = fmaf(a, w, accA[j]);
            accB[j] = fmaf(b, w, accB[j]);
        }
    }
    if (hasA) {
#pragma unroll
        for (int j = 0; j < HID; ++j) h1[(long long)r0 * HID + j] = accA[j];
    }
    if (hasB) {
#pragma unroll
        for (int j = 0; j < HID; ++j) h1[(long long)r1 * HID + j] = accB[j];
    }
}

// ---- propagate layer 1: agg1[dst][j] += h1[src][j] * dinv[src]*dinv[dst] ----
// 16 consecutive lanes handle one edge (coalesced 64B gather + 64B scatter-add)
__global__ __launch_bounds__(256) void k_prop1(const int* __restrict__ src,
                                               const int* __restrict__ dst,
                                               const float* __restrict__ dinv,
                                               const float* __restrict__ h1,
                                               float* __restrict__ agg1, int E) {
    int gid = blockIdx.x * 256 + threadIdx.x;
    int e = gid >> 4;
    int j = gid & 15;
    if (e < E) {
        int s = src[e], d = dst[e];
        float norm = dinv[s] * dinv[d];
        atomicAdd(&agg1[(long long)d * HID + j], h1[(long long)s * HID + j] * norm);
    }
}

// ---- epilogue1 + GEMM2 fused: h2 = relu(agg1 + h1*dinv^2 + b1) @ W2 ----
__global__ __launch_bounds__(256) void k_fin1(const float* __restrict__ agg1,
                                              const float* __restrict__ h1,
                                              const float* __restrict__ dinv,
                                              const float* __restrict__ b1,
                                              const float* __restrict__ W2,
                                              float* __restrict__ h2, int N) {
    int i = blockIdx.x * 256 + threadIdx.x;
    if (i >= N) return;
    float di = dinv[i];
    float d2 = di * di;
    float c0 = 0.f, c1 = 0.f;
#pragma unroll
    for (int j = 0; j < HID; ++j) {
        float v = agg1[(long long)i * HID + j] + h1[(long long)i * HID + j] * d2 + b1[j];
        v = v > 0.f ? v : 0.f;
        c0 = fmaf(v, W2[j * 2 + 0], c0);
        c1 = fmaf(v, W2[j * 2 + 1], c1);
    }
    h2[i * 2 + 0] = c0;
    h2[i * 2 + 1] = c1;
}

// ---- propagate layer 2: 2 lanes per edge ----
__global__ __launch_bounds__(256) void k_prop2(const int* __restrict__ src,
                                               const int* __restrict__ dst,
                                               const float* __restrict__ dinv,
                                               const float* __restrict__ h2,
                                               float* __restrict__ agg2, int E) {
    int gid = blockIdx.x * 256 + threadIdx.x;
    int e = gid >> 1;
    int j = gid & 1;
    if (e < E) {
        int s = src[e], d = dst[e];
        float norm = dinv[s] * dinv[d];
        atomicAdd(&agg2[(long long)d * NCLS + j], h2[(long long)s * NCLS + j] * norm);
    }
}

// ---- epilogue2 + log_softmax ----
__global__ __launch_bounds__(256) void k_fin2(const float* __restrict__ agg2,
                                              const float* __restrict__ h2,
                                              const float* __restrict__ dinv,
                                              const float* __restrict__ b2,
                                              float* __restrict__ out, int N) {
    int i = blockIdx.x * 256 + threadIdx.x;
    if (i >= N) return;
    float di = dinv[i];
    float d2 = di * di;
    float a = agg2[i * 2 + 0] + h2[i * 2 + 0] * d2 + b2[0];
    float b = agg2[i * 2 + 1] + h2[i * 2 + 1] * d2 + b2[1];
    float m = fmaxf(a, b);
    float lse = m + logf(expf(a - m) + expf(b - m));
    out[i * 2 + 0] = a - lse;
    out[i * 2 + 1] = b - lse;
}

extern "C" void kernel_launch(void* const* d_in, const int* in_sizes, int n_in,
                              void* d_out, int out_size, void* d_ws, size_t ws_size,
                              hipStream_t stream) {
    const float* x  = (const float*)d_in[0];
    const int*   ei = (const int*)d_in[1];
    const float* W1 = (const float*)d_in[2];
    const float* b1 = (const float*)d_in[3];
    const float* W2 = (const float*)d_in[4];
    const float* b2 = (const float*)d_in[5];
    float* out = (float*)d_out;

    int N = in_sizes[0] / F_IN;
    int E = in_sizes[1] / 2;
    const int* src = ei;
    const int* dst = ei + E;

    float* ws   = (float*)d_ws;
    float* dinv = ws;                         // N floats (deg -> dinv_sqrt)
    float* h1   = dinv + N;                   // 16N
    float* agg1 = h1 + (long long)16 * N;     // 16N
    float* h2   = agg1 + (long long)16 * N;   // 2N
    float* agg2 = h2 + (long long)2 * N;      // 2N

    hipMemsetAsync(dinv, 0, (size_t)N * sizeof(float), stream);
    hipMemsetAsync(agg1, 0, (size_t)N * HID * sizeof(float), stream);
    hipMemsetAsync(agg2, 0, (size_t)N * NCLS * sizeof(float), stream);

    k_deg<<<(E + 255) / 256, 256, 0, stream>>>(dst, dinv, E);
    k_dinv<<<(N + 255) / 256, 256, 0, stream>>>(dinv, N);
    k_gemm1<<<(N + 511) / 512, 256, 0, stream>>>(x, W1, h1, N);

    long long tot1 = (long long)E * 16;
    k_prop1<<<(int)((tot1 + 255) / 256), 256, 0, stream>>>(src, dst, dinv, h1, agg1, E);
    k_fin1<<<(N + 255) / 256, 256, 0, stream>>>(agg1, h1, dinv, b1, W2, h2, N);

    long long tot2 = (long long)E * 2;
    k_prop2<<<(int)((tot2 + 255) / 256), 256, 0, stream>>>(src, dst, dinv, h2, agg2, E);
    k_fin2<<<(N + 255) / 256, 256, 0, stream>>>(agg2, h2, dinv, b2, out, N);
}

// Round 2
// 583.921 us; speedup vs baseline: 1.0271x; 1.0271x over previous
//
#include <hip/hip_runtime.h>
#include <math.h>

#define F_IN 165
#define HID 16
#define NCLS 2

// ---- count in-degree (int atomics) ----
__global__ __launch_bounds__(256) void k_count(const int* __restrict__ dst,
                                               int* __restrict__ cnt, int E) {
    int i = blockIdx.x * 256 + threadIdx.x;
    if (i < E) atomicAdd(&cnt[dst[i]], 1);
}

// ---- scan phase A: per-block inclusive scan + block sums ----
__global__ __launch_bounds__(256) void k_scanA(const int* __restrict__ cnt,
                                               int* __restrict__ scn,
                                               int* __restrict__ bsum, int N) {
    __shared__ int s[256];
    int t = threadIdx.x;
    int i = blockIdx.x * 256 + t;
    int c = (i < N) ? cnt[i] : 0;
    s[t] = c;
    __syncthreads();
    for (int off = 1; off < 256; off <<= 1) {
        int a = (t >= off) ? s[t - off] : 0;
        __syncthreads();
        s[t] += a;
        __syncthreads();
    }
    if (i < N) scn[i] = s[t];
    if (t == 255) bsum[blockIdx.x] = s[255];
}

// ---- scan phase B: single-block exclusive scan of block sums ----
__global__ __launch_bounds__(512) void k_scanB(const int* __restrict__ bsum,
                                               int* __restrict__ boffs, int NB) {
    __shared__ int s[512];
    int t = threadIdx.x;
    int v = (t < NB) ? bsum[t] : 0;
    s[t] = v;
    __syncthreads();
    for (int off = 1; off < 512; off <<= 1) {
        int a = (t >= off) ? s[t - off] : 0;
        __syncthreads();
        s[t] += a;
        __syncthreads();
    }
    if (t < NB) boffs[t] = s[t] - v;
}

// ---- scan phase C: rowptr / cursor / dinv ----
__global__ __launch_bounds__(256) void k_scanC(const int* __restrict__ cnt,
                                               const int* __restrict__ scn,
                                               const int* __restrict__ boffs,
                                               int* __restrict__ rowptr,
                                               int* __restrict__ cursor,
                                               float* __restrict__ dinv, int N) {
    int i = blockIdx.x * 256 + threadIdx.x;
    if (i >= N) return;
    int c = cnt[i];
    int excl = boffs[blockIdx.x] + scn[i] - c;
    rowptr[i] = excl;
    cursor[i] = excl;
    dinv[i] = rsqrtf((float)c + 1.0f);
    if (i == N - 1) rowptr[N] = excl + c;
}

// ---- scatter edges into CSR slots ----
__global__ __launch_bounds__(256) void k_scatter(const int* __restrict__ src,
                                                 const int* __restrict__ dst,
                                                 int* __restrict__ cursor,
                                                 int* __restrict__ csr, int E) {
    int i = blockIdx.x * 256 + threadIdx.x;
    if (i < E) {
        int p = atomicAdd(&cursor[dst[i]], 1);
        csr[p] = src[i];
    }
}

// ---- g1 = (x @ W1) * dinv[row]   (LDS-tiled, 64 rows/block) ----
__global__ __launch_bounds__(256) void k_gemm1(const float* __restrict__ x,
                                               const float* __restrict__ W1,
                                               const float* __restrict__ dinv,
                                               float* __restrict__ g1, int N) {
    __shared__ float xs[64 * F_IN];
    int b = blockIdx.x;
    int rows = min(64, N - b * 64);
    int nf = rows * F_IN;
    const float* xbase = x + (long long)b * 64 * F_IN;
    int nf4 = nf >> 2;  // tile start is 16B-aligned (64*165*4 = 42240 % 16 == 0)
    const float4* src4 = (const float4*)xbase;
    float4* xs4 = (float4*)xs;
    for (int i = threadIdx.x; i < nf4; i += 256) xs4[i] = src4[i];
    for (int i = nf4 * 4 + threadIdx.x; i < nf; i += 256) xs[i] = xbase[i];
    __syncthreads();

    int row = threadIdx.x & 63;
    int jq = threadIdx.x >> 6;  // wave-uniform -> W1 via scalar loads
    int gi = b * 64 + row;
    if (gi < N && row < rows) {
        float a0 = 0.f, a1 = 0.f, a2 = 0.f, a3 = 0.f;
        for (int k = 0; k < F_IN; ++k) {
            float v = xs[row * F_IN + k];  // bank stride 5 -> conflict-free
            const float* w = W1 + k * HID + jq * 4;
            a0 = fmaf(v, w[0], a0);
            a1 = fmaf(v, w[1], a1);
            a2 = fmaf(v, w[2], a2);
            a3 = fmaf(v, w[3], a3);
        }
        float di = dinv[gi];
        float* o = g1 + (long long)gi * HID + jq * 4;
        o[0] = a0 * di; o[1] = a1 * di; o[2] = a2 * di; o[3] = a3 * di;
    }
}

// ---- gather layer 1 + bias + relu + W2 + rescale: g2 = relu(...)@W2 * dinv ----
// 16 lanes per node: lane j = feature j; each edge = one coalesced 64B row read
__global__ __launch_bounds__(256) void k_gather1(const int* __restrict__ rowptr,
                                                 const int* __restrict__ csr,
                                                 const float* __restrict__ g1,
                                                 const float* __restrict__ dinv,
                                                 const float* __restrict__ b1,
                                                 const float* __restrict__ W2,
                                                 float* __restrict__ g2, int N) {
    int gid = blockIdx.x * 256 + threadIdx.x;
    int i = gid >> 4;
    int j = gid & 15;
    if (i >= N) return;
    int e0 = rowptr[i], e1 = rowptr[i + 1];
    float acc = g1[(long long)i * HID + j];  // self-loop term
    for (int e = e0; e < e1; ++e) {
        int s = csr[e];
        acc += g1[(long long)s * HID + j];
    }
    float di = dinv[i];
    float v = acc * di + b1[j];
    v = v > 0.f ? v : 0.f;
    float c0 = v * W2[j * 2 + 0];
    float c1 = v * W2[j * 2 + 1];
    for (int off = 8; off; off >>= 1) {
        c0 += __shfl_xor(c0, off, 16);
        c1 += __shfl_xor(c1, off, 16);
    }
    if (j == 0) g2[(long long)i * 2 + 0] = c0 * di;
    if (j == 1) g2[(long long)i * 2 + 1] = c1 * di;
}

// ---- gather layer 2 + bias + log_softmax ----
// 8 lanes per node: lane = (edge-slot eo=0..3, class j=0..1)
__global__ __launch_bounds__(256) void k_gather2(const int* __restrict__ rowptr,
                                                 const int* __restrict__ csr,
                                                 const float* __restrict__ g2,
                                                 const float* __restrict__ dinv,
                                                 const float* __restrict__ b2,
                                                 float* __restrict__ out, int N) {
    int gid = blockIdx.x * 256 + threadIdx.x;
    int i = gid >> 3;
    int l = gid & 7;
    if (i >= N) return;
    int j = l & 1;
    int eo = l >> 1;
    int e0 = rowptr[i], e1 = rowptr[i + 1];
    float acc = (eo == 0) ? g2[(long long)i * 2 + j] : 0.f;  // self-loop
    for (int e = e0 + eo; e < e1; e += 4) {
        int s = csr[e];
        acc += g2[(long long)s * 2 + j];
    }
    acc += __shfl_xor(acc, 2, 8);
    acc += __shfl_xor(acc, 4, 8);
    float a = acc * dinv[i] + b2[j];
    float o = __shfl_xor(a, 1, 8);
    float m = fmaxf(a, o);
    float lse = m + logf(expf(a - m) + expf(o - m));
    if (l < 2) out[(long long)i * 2 + j] = a - lse;
}

extern "C" void kernel_launch(void* const* d_in, const int* in_sizes, int n_in,
                              void* d_out, int out_size, void* d_ws, size_t ws_size,
                              hipStream_t stream) {
    const float* x  = (const float*)d_in[0];
    const int*   ei = (const int*)d_in[1];
    const float* W1 = (const float*)d_in[2];
    const float* b1 = (const float*)d_in[3];
    const float* W2 = (const float*)d_in[4];
    const float* b2 = (const float*)d_in[5];
    float* out = (float*)d_out;

    int N = in_sizes[0] / F_IN;
    int E = in_sizes[1] / 2;
    const int* src = ei;
    const int* dst = ei + E;
    int NB = (N + 255) / 256;

    int* cnt    = (int*)d_ws;            // N
    int* rowptr = cnt + N;               // N+1
    int* cursor = rowptr + N + 1;        // N
    int* bsum   = cursor + N;            // NB
    int* boffs  = bsum + NB;             // NB
    int* scn    = boffs + NB;            // N
    int* csr    = scn + N;               // E
    float* dinv = (float*)(csr + E);     // N
    float* g1   = dinv + N;              // 16N
    float* g2   = g1 + (long long)16 * N;// 2N

    hipMemsetAsync(cnt, 0, (size_t)N * sizeof(int), stream);

    k_count<<<(E + 255) / 256, 256, 0, stream>>>(dst, cnt, E);
    k_scanA<<<NB, 256, 0, stream>>>(cnt, scn, bsum, N);
    k_scanB<<<1, 512, 0, stream>>>(bsum, boffs, NB);
    k_scanC<<<NB, 256, 0, stream>>>(cnt, scn, boffs, rowptr, cursor, dinv, N);
    k_scatter<<<(E + 255) / 256, 256, 0, stream>>>(src, dst, cursor, csr, E);

    k_gemm1<<<(N + 63) / 64, 256, 0, stream>>>(x, W1, dinv, g1, N);

    long long t1 = (long long)N * 16;
    k_gather1<<<(int)((t1 + 255) / 256), 256, 0, stream>>>(rowptr, csr, g1, dinv, b1, W2, g2, N);

    long long t2 = (long long)N * 8;
    k_gather2<<<(int)((t2 + 255) / 256), 256, 0, stream>>>(rowptr, csr, g2, dinv, b2, out, N);
}